// Round 9
// baseline (69824.603 us; speedup 1.0000x reference)
//
#include <hip/hip_runtime.h>
#include <math.h>

// ---------------------------------------------------------------------------
// R9: XCD-local pipeline, transport corrected after R8's diagnosis.
// R8 failed with absmax 1.07e-2 + ~16s limp: hand-rolled `sc0` flag loads do
// NOT reliably bypass the consumer's L1 on gfx950 -> polled flag lines stuck
// stale -> bounded-spin bailouts -> h(t-4) read as h(t). Fix:
//   - FLAGS: __hip_atomic_load/store RELAXED AGENT (R3/R5-proven coherent,
//     8192+ sync rounds clean). Single-writer seq numbers, 128B lines,
//     wave-wide poll. No RMW in the hot loop.
//   - DATA: plain float4 stores -> write-through L1 -> XCD L2, drained with
//     s_waitcnt vmcnt(0) BEFORE the flag store (flag visible => data in L2);
//     consumers run `buffer_inv` (vector-L1-only invalidate) after a
//     successful wait, then plain coalesced float4 loads (L1 miss -> L2 hit).
//     Bulk path never touches agent scope => no LLC trips, no L2 flushes.
// Placement: s_getreg(HW_REG_XCC_ID) + per-XCD role claim; 149KB LDS +
// grid=256 => 1 block/CU => exactly 32 blocks/XCD (G16-safe: no assumption
// about blockIdx->XCD). hh weights LDS-resident; ih weights stream from L2.
// Bounded spin kept as deadlock diagnostic (bail -> absmax, not hang).
// ---------------------------------------------------------------------------

__device__ __forceinline__ float sigmoidf_(float v) {
    return 1.0f / (1.0f + __expf(-v));
}

// src[(g*H+u)*J + j] -> dst[(u*3+g)*J + j]
__global__ void prep_k(const float* __restrict__ src, float* __restrict__ dst,
                       int H, int J) {
    int idx = blockIdx.x * 256 + threadIdx.x;
    int total = 3 * H * J;
    if (idx < total) {
        int g = idx / (H * J);
        int rem = idx - g * H * J;
        int u = rem / J;
        int j = rem - u * J;
        dst[(u * 3 + g) * J + j] = src[(g * H + u) * J + j];
    }
}

// ---- transport primitives --------------------------------------------------

__device__ __forceinline__ void flag_st(int* p, int v) {
    __hip_atomic_store(p, v, __ATOMIC_RELAXED, __HIP_MEMORY_SCOPE_AGENT);
}
__device__ __forceinline__ int flag_ld(const int* p) {
    return __hip_atomic_load(p, __ATOMIC_RELAXED, __HIP_MEMORY_SCOPE_AGENT);
}

// invalidate this CU's vector L1 so subsequent plain loads observe peer
// CUs' stores via the shared XCD L2. LDS contents unaffected.
__device__ __forceinline__ void l1_inv() {
    asm volatile("buffer_inv" ::: "memory");
}

// wave0 polls per-lane flag words until all satisfy flag >= tgt, then the
// whole block invalidates L1 (acquire for the plain-load data path).
// Bounded spin: pathological non-arrival degrades to absmax, not a hang.
__device__ __forceinline__ void pollwait(const int* p, int tgt) {
    if (threadIdx.x < 64) {
        int spins = 0;
        while (true) {
            int v = flag_ld(p);
            if (__all(v >= tgt)) break;
            if (++spins > 150000) break;
            __builtin_amdgcn_s_sleep(2);
        }
    }
    __syncthreads();
    l1_inv();
}

// stage 32 rows of J floats from the exchange ring (contiguous [b][u]) into
// LDS rows of stride J+4, via plain coalesced float4 loads (post-buffer_inv).
template <int J>
__device__ __forceinline__ void stageX(float* dst, const float* src) {
    constexpr int NF4 = (32 * J) / 1024;  // 8 for J=256, 4 for J=128
    constexpr int LJ = (J == 256) ? 8 : 7;
    #pragma unroll
    for (int k = 0; k < NF4; ++k) {
        int i = (k * 256 + threadIdx.x) * 4;
        float4 v = *(const float4*)(src + i);
        int b = i >> LJ;
        int j = i & (J - 1);
        *(float4*)(dst + b * (J + 4) + j) = v;
    }
}

template <int J>
__device__ __forceinline__ void zero32(float* dst) {
    for (int i = threadIdx.x; i < 32 * (J + 4); i += 256) dst[i] = 0.0f;
}

// acc{r,z,c} += w{R,Z,N} . h[row] for KB batch rows (row = b0 + k*(32/KB))
template <int KB, int J>
__device__ __forceinline__ void dot3(const float* __restrict__ w3,
                                     const float* __restrict__ hst, int b0,
                                     float* ar, float* az, float* ac) {
    const float4* wr = (const float4*)w3;
    const float4* wz = (const float4*)(w3 + J);
    const float4* wn = (const float4*)(w3 + 2 * J);
    const float* rows[KB];
    #pragma unroll
    for (int k = 0; k < KB; ++k) rows[k] = hst + (b0 + k * (32 / KB)) * (J + 4);
    #pragma unroll 4
    for (int j4 = 0; j4 < J / 4; ++j4) {
        float4 a = wr[j4];
        float4 c = wz[j4];
        float4 d = wn[j4];
        #pragma unroll
        for (int k = 0; k < KB; ++k) {
            float4 hv = *(const float4*)(rows[k] + j4 * 4);
            ar[k] = fmaf(hv.x, a.x, ar[k]); ar[k] = fmaf(hv.y, a.y, ar[k]);
            ar[k] = fmaf(hv.z, a.z, ar[k]); ar[k] = fmaf(hv.w, a.w, ar[k]);
            az[k] = fmaf(hv.x, c.x, az[k]); az[k] = fmaf(hv.y, c.y, az[k]);
            az[k] = fmaf(hv.z, c.z, az[k]); az[k] = fmaf(hv.w, c.w, az[k]);
            ac[k] = fmaf(hv.x, d.x, ac[k]); ac[k] = fmaf(hv.y, d.y, ac[k]);
            ac[k] = fmaf(hv.z, d.z, ac[k]); ac[k] = fmaf(hv.w, d.w, ac[k]);
        }
    }
}

__global__ __launch_bounds__(256) void gru_xcd_kernel(
    const float* __restrict__ x,
    const float* __restrict__ w_ih1,
    const float* __restrict__ b_ih1, const float* __restrict__ b_hh1,
    const float* __restrict__ b_ih2, const float* __restrict__ b_hh2,
    const float* __restrict__ b_ih3, const float* __restrict__ b_hh3,
    const float* __restrict__ b_ih4, const float* __restrict__ b_hh4,
    const float* __restrict__ wA_hh1,  // [256][3][256]
    const float* __restrict__ wA_ih2,  // [128][3][256]
    const float* __restrict__ wA_hh2,  // [128][3][128]
    const float* __restrict__ wA_ih3,  // [128][3][128]
    const float* __restrict__ wA_hh3,  // [128][3][128]
    const float* __restrict__ wA_ih4,  // [256][3][128]
    const float* __restrict__ wA_hh4,  // [256][3][256]
    const float* __restrict__ w_out, const float* __restrict__ b_out,
    int* __restrict__ flags,  // [8 xcd][96 words x 32 ints]
    int* __restrict__ rctr,   // [8] role counters
    float* __restrict__ ex,   // [8 xcd][98304] h rings
    float* __restrict__ out)  // [256][1024] pre-zeroed
{
    const int tid = threadIdx.x;
    extern __shared__ float smem[];
    __shared__ float xs[32];
    __shared__ float wsum[4][4][8];
    __shared__ int role_s, xcd_s;

    if (tid == 0) {
        int xcd;
        asm volatile("s_getreg_b32 %0, hwreg(HW_REG_XCC_ID)" : "=s"(xcd));
        xcd_s = xcd & 7;
        role_s = atomicAdd(&rctr[xcd & 7], 1);
    }
    __syncthreads();
    const int xcd = xcd_s;
    const int role = role_s & 31;
    const int s = role >> 3;   // stage 0..3
    const int us = role & 7;   // unit slice 0..7

    int* fb = flags + xcd * 3072;
#define ARRW(ss, uu)  (fb + ((ss) * 8 + (uu)) * 32)
#define ACKPW(ss, uu) (fb + (32 + (ss) * 8 + (uu)) * 32)
#define ACKDW(ss, uu) (fb + (64 + (ss) * 8 + (uu)) * 32)

    float* exb = ex + (size_t)xcd * 98304;
    float* h1r = exb;            // 4 slots x 32 x 256
    float* h2r = exb + 32768;    // 4 x 32 x 128
    float* h3r = exb + 49152;
    float* h4r = exb + 65536;

    int* arr_self  = ARRW(s, us);
    int* ackp_self = ACKPW(s, us);
    int* ackd_self = (s > 0) ? ACKDW(s - 1, us) : nullptr;

    const int* pollp = arr_self;
    int dlt = -1000000;
    if (tid < 64) {
        int l = tid;
        if (l < 8)       { if (s > 0) { pollp = ARRW(s - 1, l); dlt = 1; } }
        else if (l < 16) { pollp = ARRW(s, l - 8);  dlt = 0; }
        else if (l < 24) { pollp = ACKPW(s, l - 16); dlt = -3; }
        else if (l < 32) { if (s < 3) { pollp = ACKDW(s, l - 24); dlt = -3; } }
    }

    if (s == 0) {
        // ---- layer 1: in=1 scalar, H=256, 32 units/slice, KB=4 ----
        float* wlds = smem;            // [32][772]
        float* hprev = smem + 24704;   // [32][260]
        {
            const float* srcw = wA_hh1 + (size_t)us * 32 * 768;
            for (int i = tid; i < 24576; i += 256) {
                int uu = i / 768, r = i - uu * 768;
                wlds[uu * 772 + r] = srcw[i];
            }
        }
        __syncthreads();
        const int ul = tid >> 3, b0 = tid & 7;
        const int u = us * 32 + ul;
        const float* wh = wlds + ul * 772;
        const float br = b_ih1[u] + b_hh1[u];
        const float bz = b_ih1[u + 256] + b_hh1[u + 256];
        const float bxn = b_ih1[u + 512];
        const float bhn = b_hh1[u + 512];
        const float wir = w_ih1[u], wiz = w_ih1[u + 256], win = w_ih1[u + 512];
        for (int t = 0; t < 1024; ++t) {
            pollwait(pollp, t + dlt);
            if (tid < 32) xs[tid] = x[(size_t)(xcd * 32 + tid) * 1024 + t];
            if (t > 0) stageX<256>(hprev, h1r + (size_t)((t - 1) & 3) * 8192);
            else       zero32<256>(hprev);
            __syncthreads();
            if (tid == 0) flag_st(ackp_self, t);
            float ar[4], az[4], axn[4], ahn[4];
            #pragma unroll
            for (int k = 0; k < 4; ++k) {
                float xv = xs[b0 + 8 * k];
                ar[k] = br + xv * wir; az[k] = bz + xv * wiz;
                axn[k] = bxn + xv * win; ahn[k] = bhn;
            }
            dot3<4, 256>(wh, hprev, b0, ar, az, ahn);
            float* hout = h1r + (size_t)(t & 3) * 8192;
            #pragma unroll
            for (int k = 0; k < 4; ++k) {
                int b = b0 + 8 * k;
                float hp = hprev[b * 260 + u];
                float r = sigmoidf_(ar[k]);
                float z = sigmoidf_(az[k]);
                float n = tanhf(axn[k] + r * ahn[k]);
                hout[b * 256 + u] = (1.f - z) * n + z * hp;
            }
            asm volatile("s_waitcnt vmcnt(0)" ::: "memory");  // h in XCD L2
            __syncthreads();
            if (tid == 0) flag_st(arr_self, t + 1);
        }
    } else if (s == 1) {
        // ---- layer 2: in=256, H=128, 16 units/slice, KB=2 ----
        float* wlds = smem;            // [16][388]
        float* hin = smem + 6208;      // [32][260]
        float* hprev = smem + 14528;   // [32][132]
        {
            const float* srcw = wA_hh2 + (size_t)us * 16 * 384;
            for (int i = tid; i < 6144; i += 256) {
                int uu = i / 384, r = i - uu * 384;
                wlds[uu * 388 + r] = srcw[i];
            }
        }
        __syncthreads();
        const int ul = tid >> 4, b0 = tid & 15;
        const int u = us * 16 + ul;
        const float* wi = wA_ih2 + (size_t)u * 768;
        const float* wh = wlds + ul * 388;
        const float br = b_ih2[u] + b_hh2[u];
        const float bz = b_ih2[u + 128] + b_hh2[u + 128];
        const float bxn = b_ih2[u + 256];
        const float bhn = b_hh2[u + 256];
        for (int t = 0; t < 1024; ++t) {
            pollwait(pollp, t + dlt);
            stageX<256>(hin, h1r + (size_t)(t & 3) * 8192);
            if (t > 0) stageX<128>(hprev, h2r + (size_t)((t - 1) & 3) * 4096);
            else       zero32<128>(hprev);
            __syncthreads();
            if (tid == 0) { flag_st(ackp_self, t); flag_st(ackd_self, t + 1); }
            float ar[2] = {br, br}, az[2] = {bz, bz};
            float axn[2] = {bxn, bxn}, ahn[2] = {bhn, bhn};
            dot3<2, 256>(wi, hin, b0, ar, az, axn);
            dot3<2, 128>(wh, hprev, b0, ar, az, ahn);
            float* hout = h2r + (size_t)(t & 3) * 4096;
            #pragma unroll
            for (int k = 0; k < 2; ++k) {
                int b = b0 + 16 * k;
                float hp = hprev[b * 132 + u];
                float r = sigmoidf_(ar[k]);
                float z = sigmoidf_(az[k]);
                float n = tanhf(axn[k] + r * ahn[k]);
                hout[b * 128 + u] = (1.f - z) * n + z * hp;
            }
            asm volatile("s_waitcnt vmcnt(0)" ::: "memory");
            __syncthreads();
            if (tid == 0) flag_st(arr_self, t + 1);
        }
    } else if (s == 2) {
        // ---- layer 3: in=128, H=128, 16 units/slice, KB=2 ----
        float* wlds = smem;            // [16][388]
        float* hin = smem + 6208;      // [32][132]
        float* hprev = smem + 10432;   // [32][132]
        {
            const float* srcw = wA_hh3 + (size_t)us * 16 * 384;
            for (int i = tid; i < 6144; i += 256) {
                int uu = i / 384, r = i - uu * 384;
                wlds[uu * 388 + r] = srcw[i];
            }
        }
        __syncthreads();
        const int ul = tid >> 4, b0 = tid & 15;
        const int u = us * 16 + ul;
        const float* wi = wA_ih3 + (size_t)u * 384;
        const float* wh = wlds + ul * 388;
        const float br = b_ih3[u] + b_hh3[u];
        const float bz = b_ih3[u + 128] + b_hh3[u + 128];
        const float bxn = b_ih3[u + 256];
        const float bhn = b_hh3[u + 256];
        for (int t = 0; t < 1024; ++t) {
            pollwait(pollp, t + dlt);
            stageX<128>(hin, h2r + (size_t)(t & 3) * 4096);
            if (t > 0) stageX<128>(hprev, h3r + (size_t)((t - 1) & 3) * 4096);
            else       zero32<128>(hprev);
            __syncthreads();
            if (tid == 0) { flag_st(ackp_self, t); flag_st(ackd_self, t + 1); }
            float ar[2] = {br, br}, az[2] = {bz, bz};
            float axn[2] = {bxn, bxn}, ahn[2] = {bhn, bhn};
            dot3<2, 128>(wi, hin, b0, ar, az, axn);
            dot3<2, 128>(wh, hprev, b0, ar, az, ahn);
            float* hout = h3r + (size_t)(t & 3) * 4096;
            #pragma unroll
            for (int k = 0; k < 2; ++k) {
                int b = b0 + 16 * k;
                float hp = hprev[b * 132 + u];
                float r = sigmoidf_(ar[k]);
                float z = sigmoidf_(az[k]);
                float n = tanhf(axn[k] + r * ahn[k]);
                hout[b * 128 + u] = (1.f - z) * n + z * hp;
            }
            asm volatile("s_waitcnt vmcnt(0)" ::: "memory");
            __syncthreads();
            if (tid == 0) flag_st(arr_self, t + 1);
        }
    } else {
        // ---- layer 4: in=128, H=256, 32 units/slice, KB=4, + projection ----
        float* wlds = smem;            // [32][772]
        float* hin = smem + 24704;     // [32][132]
        float* hprev = smem + 28928;   // [32][260]
        {
            const float* srcw = wA_hh4 + (size_t)us * 32 * 768;
            for (int i = tid; i < 24576; i += 256) {
                int uu = i / 768, r = i - uu * 768;
                wlds[uu * 772 + r] = srcw[i];
            }
        }
        __syncthreads();
        const int ul = tid >> 3, b0 = tid & 7;
        const int u = us * 32 + ul;
        const float* wi = wA_ih4 + (size_t)u * 384;
        const float* wh = wlds + ul * 772;
        const float br = b_ih4[u] + b_hh4[u];
        const float bz = b_ih4[u + 256] + b_hh4[u + 256];
        const float bxn = b_ih4[u + 512];
        const float bhn = b_hh4[u + 512];
        const float wo = w_out[u];
        for (int t = 0; t < 1024; ++t) {
            pollwait(pollp, t + dlt);
            stageX<128>(hin, h3r + (size_t)(t & 3) * 4096);
            if (t > 0) stageX<256>(hprev, h4r + (size_t)((t - 1) & 3) * 8192);
            else       zero32<256>(hprev);
            __syncthreads();
            if (tid == 0) { flag_st(ackp_self, t); flag_st(ackd_self, t + 1); }
            float ar[4], az[4], axn[4], ahn[4];
            #pragma unroll
            for (int k = 0; k < 4; ++k) {
                ar[k] = br; az[k] = bz; axn[k] = bxn; ahn[k] = bhn;
            }
            dot3<4, 128>(wi, hin, b0, ar, az, axn);
            dot3<4, 256>(wh, hprev, b0, ar, az, ahn);
            float* hout = h4r + (size_t)(t & 3) * 8192;
            float pk[4];
            #pragma unroll
            for (int k = 0; k < 4; ++k) {
                int b = b0 + 8 * k;
                float hp = hprev[b * 260 + u];
                float r = sigmoidf_(ar[k]);
                float z = sigmoidf_(az[k]);
                float n = tanhf(axn[k] + r * ahn[k]);
                float hnew = (1.f - z) * n + z * hp;
                hout[b * 256 + u] = hnew;
                pk[k] = wo * hnew;
            }
            #pragma unroll
            for (int k = 0; k < 4; ++k) {
                pk[k] += __shfl_xor(pk[k], 8, 64);
                pk[k] += __shfl_xor(pk[k], 16, 64);
                pk[k] += __shfl_xor(pk[k], 32, 64);
            }
            if ((tid & 63) < 8) {
                int w = tid >> 6;
                #pragma unroll
                for (int k = 0; k < 4; ++k) wsum[w][k][tid & 7] = pk[k];
            }
            asm volatile("s_waitcnt vmcnt(0)" ::: "memory");
            __syncthreads();
            if (tid == 0) flag_st(arr_self, t + 1);
            if (tid < 32) {
                int k = tid >> 3, bb = tid & 7;
                float ssum = wsum[0][k][bb] + wsum[1][k][bb] +
                             wsum[2][k][bb] + wsum[3][k][bb];
                if (us == 0) ssum += b_out[0];
                atomicAdd(out + (size_t)(xcd * 32 + bb + 8 * k) * 1024 + t, ssum);
            }
        }
    }
#undef ARRW
#undef ACKPW
#undef ACKDW
}

extern "C" void kernel_launch(void* const* d_in, const int* in_sizes, int n_in,
                              void* d_out, int out_size, void* d_ws, size_t ws_size,
                              hipStream_t stream) {
    const float* x     = (const float*)d_in[0];
    const float* w_ih1 = (const float*)d_in[1];
    const float* w_hh1 = (const float*)d_in[2];
    const float* b_ih1 = (const float*)d_in[3];
    const float* b_hh1 = (const float*)d_in[4];
    const float* w_ih2 = (const float*)d_in[5];
    const float* w_hh2 = (const float*)d_in[6];
    const float* b_ih2 = (const float*)d_in[7];
    const float* b_hh2 = (const float*)d_in[8];
    const float* w_ih3 = (const float*)d_in[9];
    const float* w_hh3 = (const float*)d_in[10];
    const float* b_ih3 = (const float*)d_in[11];
    const float* b_hh3 = (const float*)d_in[12];
    const float* w_ih4 = (const float*)d_in[13];
    const float* w_hh4 = (const float*)d_in[14];
    const float* b_ih4 = (const float*)d_in[15];
    const float* b_hh4 = (const float*)d_in[16];
    const float* w_out = (const float*)d_in[17];
    const float* b_out = (const float*)d_in[18];

    float* ws = (float*)d_ws;
    float* wA_hh1 = ws;                  // 196608
    float* wA_ih2 = wA_hh1 + 196608;     //  98304
    float* wA_hh2 = wA_ih2 + 98304;      //  49152
    float* wA_ih3 = wA_hh2 + 49152;      //  49152
    float* wA_hh3 = wA_ih3 + 49152;      //  49152
    float* wA_ih4 = wA_hh3 + 49152;      //  98304
    float* wA_hh4 = wA_ih4 + 98304;      // 196608
    float* ex     = wA_hh4 + 196608;     // 786432 (8 XCD x 98304)
    int*   flags  = (int*)(ex + 786432); // 8 x 3072 ints
    int*   rctr   = flags + 24576;       // 8 ints

    hipMemsetAsync(flags, 0, (24576 + 8) * sizeof(int), stream);
    hipMemsetAsync(d_out, 0, 256 * 1024 * sizeof(float), stream);

    prep_k<<<768, 256, 0, stream>>>(w_hh1, wA_hh1, 256, 256);
    prep_k<<<384, 256, 0, stream>>>(w_ih2, wA_ih2, 128, 256);
    prep_k<<<192, 256, 0, stream>>>(w_hh2, wA_hh2, 128, 128);
    prep_k<<<192, 256, 0, stream>>>(w_ih3, wA_ih3, 128, 128);
    prep_k<<<192, 256, 0, stream>>>(w_hh3, wA_hh3, 128, 128);
    prep_k<<<384, 256, 0, stream>>>(w_ih4, wA_ih4, 256, 128);
    prep_k<<<768, 256, 0, stream>>>(w_hh4, wA_hh4, 256, 256);

    // 149KB dynamic LDS: 1 block/CU, grid=256 => exactly 32 blocks/XCD.
    const int dyn_lds = 37248 * (int)sizeof(float);
    (void)hipFuncSetAttribute((const void*)gru_xcd_kernel,
                              hipFuncAttributeMaxDynamicSharedMemorySize, dyn_lds);

    gru_xcd_kernel<<<256, 256, dyn_lds, stream>>>(
        x, w_ih1, b_ih1, b_hh1, b_ih2, b_hh2, b_ih3, b_hh3, b_ih4, b_hh4,
        wA_hh1, wA_ih2, wA_hh2, wA_ih3, wA_hh3, wA_ih4, wA_hh4,
        w_out, b_out, flags, rctr, ex, (float*)d_out);
}

// Round 10
// 69083.936 us; speedup vs baseline: 1.0107x; 1.0107x over previous
//
#include <hip/hip_runtime.h>
#include <math.h>

// ---------------------------------------------------------------------------
// R10: XCD-local pipeline, R9's (correctness-proven) data transport + a
// minimal single-line flag fabric.
// R9 post-mortem: data path hit all goals (WRITE 1.14GB->91MB) but 93% of
// time was flag-wait: 32 flags on 32 distinct 128B lines polled via agent
// atomics (1 LLC transaction per lane per iteration) x4 waits/beat, with all
// waits merged at top (peer latency unhidden). Protocol re-audit: ACKP is
// subsumed by the peer-arrive wait (peer >= t-1 => staged slot t&3 at t-3);
// ACKD is subsumed by downstream arr >= t-3 (completed t-4 => staged t-4).
// So: ONLY arr[stage][8], packed 8 seq numbers per 128B line, single-writer.
//   top wait : upstream arr >= t+1 (lanes 0-7) + downstream arr >= t-3
//              (lanes 8-15) -> 2 lines total.
//   mid wait : peer arr >= t (lanes 0-7, 1 line) AFTER the ih dot (hidden).
// Data: plain float4 stores -> XCD L2 (vmcnt(0) before flag store);
// consumers buffer_inv (L1-only) after each successful wait, then plain
// coalesced loads. Agent-scope atomics ONLY for the 4-line flag fabric.
// Placement: s_getreg(HW_REG_XCC_ID) role claim; 149KB LDS + grid=256 =>
// 1 block/CU => exactly 32 blocks/XCD (G16-safe). hh weights LDS-resident.
// Bounded spin kept (bail -> absmax diagnostic, not hang).
// ---------------------------------------------------------------------------

__device__ __forceinline__ float sigmoidf_(float v) {
    return 1.0f / (1.0f + __expf(-v));
}

// src[(g*H+u)*J + j] -> dst[(u*3+g)*J + j]
__global__ void prep_k(const float* __restrict__ src, float* __restrict__ dst,
                       int H, int J) {
    int idx = blockIdx.x * 256 + threadIdx.x;
    int total = 3 * H * J;
    if (idx < total) {
        int g = idx / (H * J);
        int rem = idx - g * H * J;
        int u = rem / J;
        int j = rem - u * J;
        dst[(u * 3 + g) * J + j] = src[(g * H + u) * J + j];
    }
}

// ---- transport primitives --------------------------------------------------

__device__ __forceinline__ void flag_st(int* p, int v) {
    __hip_atomic_store(p, v, __ATOMIC_RELAXED, __HIP_MEMORY_SCOPE_AGENT);
}
__device__ __forceinline__ int flag_ld(const int* p) {
    return __hip_atomic_load(p, __ATOMIC_RELAXED, __HIP_MEMORY_SCOPE_AGENT);
}
// invalidate this CU's vector L1 (LDS unaffected); acquire for plain loads
__device__ __forceinline__ void l1_inv() {
    asm volatile("buffer_inv" ::: "memory");
}

// wave0: active lanes poll their flag word until >= tgt (tgt is per-lane).
// Ends with block barrier + L1 invalidate. Bounded spin -> diagnostic bail.
__device__ __forceinline__ void pollwait(const int* p, int tgt, bool active) {
    if (threadIdx.x < 64) {
        int spins = 0;
        while (true) {
            int v = active ? flag_ld(p) : 0x7fffffff;
            if (__all(v >= tgt)) break;
            if (++spins > 200000) break;
            __builtin_amdgcn_s_sleep(1);
        }
    }
    __syncthreads();
    l1_inv();
}

// stage 32 rows of J floats from the exchange ring (contiguous [b][u]) into
// LDS rows of stride J+4, plain coalesced float4 loads (post-buffer_inv).
template <int J>
__device__ __forceinline__ void stageX(float* dst, const float* src) {
    constexpr int NF4 = (32 * J) / 1024;  // 8 for J=256, 4 for J=128
    constexpr int LJ = (J == 256) ? 8 : 7;
    #pragma unroll
    for (int k = 0; k < NF4; ++k) {
        int i = (k * 256 + threadIdx.x) * 4;
        float4 v = *(const float4*)(src + i);
        int b = i >> LJ;
        int j = i & (J - 1);
        *(float4*)(dst + b * (J + 4) + j) = v;
    }
}

template <int J>
__device__ __forceinline__ void zero32(float* dst) {
    for (int i = threadIdx.x; i < 32 * (J + 4); i += 256) dst[i] = 0.0f;
}

// acc{r,z,c} += w{R,Z,N} . h[row] for KB batch rows (row = b0 + k*(32/KB))
template <int KB, int J>
__device__ __forceinline__ void dot3(const float* __restrict__ w3,
                                     const float* __restrict__ hst, int b0,
                                     float* ar, float* az, float* ac) {
    const float4* wr = (const float4*)w3;
    const float4* wz = (const float4*)(w3 + J);
    const float4* wn = (const float4*)(w3 + 2 * J);
    const float* rows[KB];
    #pragma unroll
    for (int k = 0; k < KB; ++k) rows[k] = hst + (b0 + k * (32 / KB)) * (J + 4);
    #pragma unroll 4
    for (int j4 = 0; j4 < J / 4; ++j4) {
        float4 a = wr[j4];
        float4 c = wz[j4];
        float4 d = wn[j4];
        #pragma unroll
        for (int k = 0; k < KB; ++k) {
            float4 hv = *(const float4*)(rows[k] + j4 * 4);
            ar[k] = fmaf(hv.x, a.x, ar[k]); ar[k] = fmaf(hv.y, a.y, ar[k]);
            ar[k] = fmaf(hv.z, a.z, ar[k]); ar[k] = fmaf(hv.w, a.w, ar[k]);
            az[k] = fmaf(hv.x, c.x, az[k]); az[k] = fmaf(hv.y, c.y, az[k]);
            az[k] = fmaf(hv.z, c.z, az[k]); az[k] = fmaf(hv.w, c.w, az[k]);
            ac[k] = fmaf(hv.x, d.x, ac[k]); ac[k] = fmaf(hv.y, d.y, ac[k]);
            ac[k] = fmaf(hv.z, d.z, ac[k]); ac[k] = fmaf(hv.w, d.w, ac[k]);
        }
    }
}

__global__ __launch_bounds__(256) void gru_xcd_kernel(
    const float* __restrict__ x,
    const float* __restrict__ w_ih1,
    const float* __restrict__ b_ih1, const float* __restrict__ b_hh1,
    const float* __restrict__ b_ih2, const float* __restrict__ b_hh2,
    const float* __restrict__ b_ih3, const float* __restrict__ b_hh3,
    const float* __restrict__ b_ih4, const float* __restrict__ b_hh4,
    const float* __restrict__ wA_hh1,  // [256][3][256]
    const float* __restrict__ wA_ih2,  // [128][3][256]
    const float* __restrict__ wA_hh2,  // [128][3][128]
    const float* __restrict__ wA_ih3,  // [128][3][128]
    const float* __restrict__ wA_hh3,  // [128][3][128]
    const float* __restrict__ wA_ih4,  // [256][3][128]
    const float* __restrict__ wA_hh4,  // [256][3][256]
    const float* __restrict__ w_out, const float* __restrict__ b_out,
    int* __restrict__ flags,  // [8 xcd][4 stages x 32 ints (128B line)]
    int* __restrict__ rctr,   // [8] role counters
    float* __restrict__ ex,   // [8 xcd][98304] h rings
    float* __restrict__ out)  // [256][1024] pre-zeroed
{
    const int tid = threadIdx.x;
    extern __shared__ float smem[];
    __shared__ float xs[32];
    __shared__ float wsum[4][4][8];
    __shared__ int role_s, xcd_s;

    if (tid == 0) {
        int xcd;
        asm volatile("s_getreg_b32 %0, hwreg(HW_REG_XCC_ID)" : "=s"(xcd));
        xcd_s = xcd & 7;
        role_s = atomicAdd(&rctr[xcd & 7], 1);
    }
    __syncthreads();
    const int xcd = xcd_s;
    const int role = role_s & 31;
    const int s = role >> 3;   // stage 0..3
    const int us = role & 7;   // unit slice 0..7

    int* fb = flags + xcd * 128;       // 4 lines x 32 ints
    int* arr_own = fb + s * 32;        // this stage's 8 seq numbers

    // per-lane poll assignments (wave0 only)
    // top: lanes 0-7 upstream arr >= t+1 ; lanes 8-15 downstream arr >= t-3
    // mid: lanes 0-7 peer arr >= t
    const int* pT = arr_own; int dT = -1000000000; bool aT = false;
    const int* pM = arr_own; int dM = -1000000000; bool aM = false;
    if (tid < 8) {
        if (s > 0) { pT = fb + (s - 1) * 32 + tid; dT = 1; aT = true; }
        pM = arr_own + tid; dM = 0; aM = true;
    } else if (tid < 16) {
        if (s < 3) { pT = fb + (s + 1) * 32 + (tid - 8); dT = -3; aT = true; }
    }

    float* exb = ex + (size_t)xcd * 98304;
    float* h1r = exb;            // 4 slots x 32 x 256
    float* h2r = exb + 32768;    // 4 x 32 x 128
    float* h3r = exb + 49152;
    float* h4r = exb + 65536;

    if (s == 0) {
        // ---- layer 1: in=1 scalar, H=256, 32 units/slice, KB=4 ----
        float* wlds = smem;            // [32][772]
        float* hprev = smem + 24704;   // [32][260]
        {
            const float* srcw = wA_hh1 + (size_t)us * 32 * 768;
            for (int i = tid; i < 24576; i += 256) {
                int uu = i / 768, r = i - uu * 768;
                wlds[uu * 772 + r] = srcw[i];
            }
        }
        __syncthreads();
        const int ul = tid >> 3, b0 = tid & 7;
        const int u = us * 32 + ul;
        const float* wh = wlds + ul * 772;
        const float br = b_ih1[u] + b_hh1[u];
        const float bz = b_ih1[u + 256] + b_hh1[u + 256];
        const float bxn = b_ih1[u + 512];
        const float bhn = b_hh1[u + 512];
        const float wir = w_ih1[u], wiz = w_ih1[u + 256], win = w_ih1[u + 512];
        for (int t = 0; t < 1024; ++t) {
            pollwait(pT, t + dT, aT);          // downstream backpressure
            if (tid < 32) xs[tid] = x[(size_t)(xcd * 32 + tid) * 1024 + t];
            pollwait(pM, t + dM, aM);          // peers done t-1 (+ l1_inv)
            if (t > 0) stageX<256>(hprev, h1r + (size_t)((t - 1) & 3) * 8192);
            else       zero32<256>(hprev);
            __syncthreads();
            float ar[4], az[4], axn[4], ahn[4];
            #pragma unroll
            for (int k = 0; k < 4; ++k) {
                float xv = xs[b0 + 8 * k];
                ar[k] = br + xv * wir; az[k] = bz + xv * wiz;
                axn[k] = bxn + xv * win; ahn[k] = bhn;
            }
            dot3<4, 256>(wh, hprev, b0, ar, az, ahn);
            float* hout = h1r + (size_t)(t & 3) * 8192;
            #pragma unroll
            for (int k = 0; k < 4; ++k) {
                int b = b0 + 8 * k;
                float hp = hprev[b * 260 + u];
                float r = sigmoidf_(ar[k]);
                float z = sigmoidf_(az[k]);
                float n = tanhf(axn[k] + r * ahn[k]);
                hout[b * 256 + u] = (1.f - z) * n + z * hp;
            }
            asm volatile("s_waitcnt vmcnt(0)" ::: "memory");  // h in XCD L2
            __syncthreads();
            if (tid == 0) flag_st(arr_own + us, t + 1);
        }
    } else if (s == 1) {
        // ---- layer 2: in=256, H=128, 16 units/slice, KB=2 ----
        float* wlds = smem;            // [16][388]
        float* hin = smem + 6208;      // [32][260]
        float* hprev = smem + 14528;   // [32][132]
        {
            const float* srcw = wA_hh2 + (size_t)us * 16 * 384;
            for (int i = tid; i < 6144; i += 256) {
                int uu = i / 384, r = i - uu * 384;
                wlds[uu * 388 + r] = srcw[i];
            }
        }
        __syncthreads();
        const int ul = tid >> 4, b0 = tid & 15;
        const int u = us * 16 + ul;
        const float* wi = wA_ih2 + (size_t)u * 768;
        const float* wh = wlds + ul * 388;
        const float br = b_ih2[u] + b_hh2[u];
        const float bz = b_ih2[u + 128] + b_hh2[u + 128];
        const float bxn = b_ih2[u + 256];
        const float bhn = b_hh2[u + 256];
        for (int t = 0; t < 1024; ++t) {
            pollwait(pT, t + dT, aT);   // upstream >= t+1, downstream >= t-3
            stageX<256>(hin, h1r + (size_t)(t & 3) * 8192);
            __syncthreads();
            float ar[2] = {br, br}, az[2] = {bz, bz};
            float axn[2] = {bxn, bxn}, ahn[2] = {bhn, bhn};
            dot3<2, 256>(wi, hin, b0, ar, az, axn);
            pollwait(pM, t + dM, aM);   // peers (hidden under ih dot)
            if (t > 0) stageX<128>(hprev, h2r + (size_t)((t - 1) & 3) * 4096);
            else       zero32<128>(hprev);
            __syncthreads();
            dot3<2, 128>(wh, hprev, b0, ar, az, ahn);
            float* hout = h2r + (size_t)(t & 3) * 4096;
            #pragma unroll
            for (int k = 0; k < 2; ++k) {
                int b = b0 + 16 * k;
                float hp = hprev[b * 132 + u];
                float r = sigmoidf_(ar[k]);
                float z = sigmoidf_(az[k]);
                float n = tanhf(axn[k] + r * ahn[k]);
                hout[b * 128 + u] = (1.f - z) * n + z * hp;
            }
            asm volatile("s_waitcnt vmcnt(0)" ::: "memory");
            __syncthreads();
            if (tid == 0) flag_st(arr_own + us, t + 1);
        }
    } else if (s == 2) {
        // ---- layer 3: in=128, H=128, 16 units/slice, KB=2 ----
        float* wlds = smem;            // [16][388]
        float* hin = smem + 6208;      // [32][132]
        float* hprev = smem + 10432;   // [32][132]
        {
            const float* srcw = wA_hh3 + (size_t)us * 16 * 384;
            for (int i = tid; i < 6144; i += 256) {
                int uu = i / 384, r = i - uu * 384;
                wlds[uu * 388 + r] = srcw[i];
            }
        }
        __syncthreads();
        const int ul = tid >> 4, b0 = tid & 15;
        const int u = us * 16 + ul;
        const float* wi = wA_ih3 + (size_t)u * 384;
        const float* wh = wlds + ul * 388;
        const float br = b_ih3[u] + b_hh3[u];
        const float bz = b_ih3[u + 128] + b_hh3[u + 128];
        const float bxn = b_ih3[u + 256];
        const float bhn = b_hh3[u + 256];
        for (int t = 0; t < 1024; ++t) {
            pollwait(pT, t + dT, aT);
            stageX<128>(hin, h2r + (size_t)(t & 3) * 4096);
            __syncthreads();
            float ar[2] = {br, br}, az[2] = {bz, bz};
            float axn[2] = {bxn, bxn}, ahn[2] = {bhn, bhn};
            dot3<2, 128>(wi, hin, b0, ar, az, axn);
            pollwait(pM, t + dM, aM);
            if (t > 0) stageX<128>(hprev, h3r + (size_t)((t - 1) & 3) * 4096);
            else       zero32<128>(hprev);
            __syncthreads();
            dot3<2, 128>(wh, hprev, b0, ar, az, ahn);
            float* hout = h3r + (size_t)(t & 3) * 4096;
            #pragma unroll
            for (int k = 0; k < 2; ++k) {
                int b = b0 + 16 * k;
                float hp = hprev[b * 132 + u];
                float r = sigmoidf_(ar[k]);
                float z = sigmoidf_(az[k]);
                float n = tanhf(axn[k] + r * ahn[k]);
                hout[b * 128 + u] = (1.f - z) * n + z * hp;
            }
            asm volatile("s_waitcnt vmcnt(0)" ::: "memory");
            __syncthreads();
            if (tid == 0) flag_st(arr_own + us, t + 1);
        }
    } else {
        // ---- layer 4: in=128, H=256, 32 units/slice, KB=4, + projection ----
        float* wlds = smem;            // [32][772]
        float* hin = smem + 24704;     // [32][132]
        float* hprev = smem + 28928;   // [32][260]
        {
            const float* srcw = wA_hh4 + (size_t)us * 32 * 768;
            for (int i = tid; i < 24576; i += 256) {
                int uu = i / 768, r = i - uu * 768;
                wlds[uu * 772 + r] = srcw[i];
            }
        }
        __syncthreads();
        const int ul = tid >> 3, b0 = tid & 7;
        const int u = us * 32 + ul;
        const float* wi = wA_ih4 + (size_t)u * 384;
        const float* wh = wlds + ul * 772;
        const float br = b_ih4[u] + b_hh4[u];
        const float bz = b_ih4[u + 256] + b_hh4[u + 256];
        const float bxn = b_ih4[u + 512];
        const float bhn = b_hh4[u + 512];
        const float wo = w_out[u];
        for (int t = 0; t < 1024; ++t) {
            pollwait(pT, t + dT, aT);   // upstream only (no downstream)
            stageX<128>(hin, h3r + (size_t)(t & 3) * 4096);
            __syncthreads();
            float ar[4], az[4], axn[4], ahn[4];
            #pragma unroll
            for (int k = 0; k < 4; ++k) {
                ar[k] = br; az[k] = bz; axn[k] = bxn; ahn[k] = bhn;
            }
            dot3<4, 128>(wi, hin, b0, ar, az, axn);
            pollwait(pM, t + dM, aM);
            if (t > 0) stageX<256>(hprev, h4r + (size_t)((t - 1) & 3) * 8192);
            else       zero32<256>(hprev);
            __syncthreads();
            dot3<4, 256>(wh, hprev, b0, ar, az, ahn);
            float* hout = h4r + (size_t)(t & 3) * 8192;
            float pk[4];
            #pragma unroll
            for (int k = 0; k < 4; ++k) {
                int b = b0 + 8 * k;
                float hp = hprev[b * 260 + u];
                float r = sigmoidf_(ar[k]);
                float z = sigmoidf_(az[k]);
                float n = tanhf(axn[k] + r * ahn[k]);
                float hnew = (1.f - z) * n + z * hp;
                hout[b * 256 + u] = hnew;
                pk[k] = wo * hnew;
            }
            #pragma unroll
            for (int k = 0; k < 4; ++k) {
                pk[k] += __shfl_xor(pk[k], 8, 64);
                pk[k] += __shfl_xor(pk[k], 16, 64);
                pk[k] += __shfl_xor(pk[k], 32, 64);
            }
            if ((tid & 63) < 8) {
                int w = tid >> 6;
                #pragma unroll
                for (int k = 0; k < 4; ++k) wsum[w][k][tid & 7] = pk[k];
            }
            asm volatile("s_waitcnt vmcnt(0)" ::: "memory");
            __syncthreads();
            if (tid == 0) flag_st(arr_own + us, t + 1);
            if (tid < 32) {
                int k = tid >> 3, bb = tid & 7;
                float ssum = wsum[0][k][bb] + wsum[1][k][bb] +
                             wsum[2][k][bb] + wsum[3][k][bb];
                if (us == 0) ssum += b_out[0];
                atomicAdd(out + (size_t)(xcd * 32 + bb + 8 * k) * 1024 + t, ssum);
            }
        }
    }
}

extern "C" void kernel_launch(void* const* d_in, const int* in_sizes, int n_in,
                              void* d_out, int out_size, void* d_ws, size_t ws_size,
                              hipStream_t stream) {
    const float* x     = (const float*)d_in[0];
    const float* w_ih1 = (const float*)d_in[1];
    const float* w_hh1 = (const float*)d_in[2];
    const float* b_ih1 = (const float*)d_in[3];
    const float* b_hh1 = (const float*)d_in[4];
    const float* w_ih2 = (const float*)d_in[5];
    const float* w_hh2 = (const float*)d_in[6];
    const float* b_ih2 = (const float*)d_in[7];
    const float* b_hh2 = (const float*)d_in[8];
    const float* w_ih3 = (const float*)d_in[9];
    const float* w_hh3 = (const float*)d_in[10];
    const float* b_ih3 = (const float*)d_in[11];
    const float* b_hh3 = (const float*)d_in[12];
    const float* w_ih4 = (const float*)d_in[13];
    const float* w_hh4 = (const float*)d_in[14];
    const float* b_ih4 = (const float*)d_in[15];
    const float* b_hh4 = (const float*)d_in[16];
    const float* w_out = (const float*)d_in[17];
    const float* b_out = (const float*)d_in[18];

    float* ws = (float*)d_ws;
    float* wA_hh1 = ws;                  // 196608
    float* wA_ih2 = wA_hh1 + 196608;     //  98304
    float* wA_hh2 = wA_ih2 + 98304;      //  49152
    float* wA_ih3 = wA_hh2 + 49152;      //  49152
    float* wA_hh3 = wA_ih3 + 49152;      //  49152
    float* wA_ih4 = wA_hh3 + 49152;      //  98304
    float* wA_hh4 = wA_ih4 + 98304;      // 196608
    float* ex     = wA_hh4 + 196608;     // 786432 (8 XCD x 98304)
    int*   flags  = (int*)(ex + 786432); // 8 x 128 ints
    int*   rctr   = flags + 1024;        // 8 ints

    hipMemsetAsync(flags, 0, (1024 + 8) * sizeof(int), stream);
    hipMemsetAsync(d_out, 0, 256 * 1024 * sizeof(float), stream);

    prep_k<<<768, 256, 0, stream>>>(w_hh1, wA_hh1, 256, 256);
    prep_k<<<384, 256, 0, stream>>>(w_ih2, wA_ih2, 128, 256);
    prep_k<<<192, 256, 0, stream>>>(w_hh2, wA_hh2, 128, 128);
    prep_k<<<192, 256, 0, stream>>>(w_ih3, wA_ih3, 128, 128);
    prep_k<<<192, 256, 0, stream>>>(w_hh3, wA_hh3, 128, 128);
    prep_k<<<384, 256, 0, stream>>>(w_ih4, wA_ih4, 256, 128);
    prep_k<<<768, 256, 0, stream>>>(w_hh4, wA_hh4, 256, 256);

    // 149KB dynamic LDS: 1 block/CU, grid=256 => exactly 32 blocks/XCD.
    const int dyn_lds = 37248 * (int)sizeof(float);
    (void)hipFuncSetAttribute((const void*)gru_xcd_kernel,
                              hipFuncAttributeMaxDynamicSharedMemorySize, dyn_lds);

    gru_xcd_kernel<<<256, 256, dyn_lds, stream>>>(
        x, w_ih1, b_ih1, b_hh1, b_ih2, b_hh2, b_ih3, b_hh3, b_ih4, b_hh4,
        wA_hh1, wA_ih2, wA_hh2, wA_ih3, wA_hh3, wA_ih4, wA_hh4,
        w_out, b_out, flags, rctr, ex, (float*)d_out);
}

// Round 11
// 18214.215 us; speedup vs baseline: 3.8335x; 3.7929x over previous
//
#include <hip/hip_runtime.h>
#include <math.h>

// ---------------------------------------------------------------------------
// R11: 4-stage layer pipeline with PROVEN LLC transport + R10's minimal flag
// fabric. R9/R10 post-mortem: both sat at ~69ms regardless of flag-fabric
// size => the stall was the data path, almost certainly bare `buffer_inv`
// invalidating the XCD L2 (gfx940+ encodes L1-inv as `buffer_inv sc0`; bare
// form hits L2) -> R2's L2-nuke poison reborn, 2x/beat. This round has ZERO
// cache-maintenance instructions:
//   - producer h-writes: __hip_atomic_store RELAXED AGENT 4B (R3/R4/R5-
//     proven: bypasses L1/L2, completes at coherent LLC), drained with
//     s_waitcnt vmcnt(0) + barrier before the flag store.
//   - consumer staging: raw `global_load_dwordx4 ... sc0 sc1` (bypass L1+L2,
//     read the LLC directly) -> line-coalesced, 4x fewer instrs than 4B
//     atomic loads.
//   - flags: R10 fabric — arr[stage] = one 128B line of 8 single-writer seq
//     numbers per batch-group; wave-wide agent-atomic poll; top wait =
//     upstream>=t+1 + downstream>=t-3; peer wait (>=t) after the ih dot.
// Roles from blockIdx (no XCD claim — LLC is chip-global). hh weights
// LDS-resident (149KB dyn LDS => 1 block/CU). Bounded spin diagnostic kept.
// ---------------------------------------------------------------------------

__device__ __forceinline__ float sigmoidf_(float v) {
    return 1.0f / (1.0f + __expf(-v));
}

// src[(g*H+u)*J + j] -> dst[(u*3+g)*J + j]
__global__ void prep_k(const float* __restrict__ src, float* __restrict__ dst,
                       int H, int J) {
    int idx = blockIdx.x * 256 + threadIdx.x;
    int total = 3 * H * J;
    if (idx < total) {
        int g = idx / (H * J);
        int rem = idx - g * H * J;
        int u = rem / J;
        int j = rem - u * J;
        dst[(u * 3 + g) * J + j] = src[(g * H + u) * J + j];
    }
}

// ---- transport primitives --------------------------------------------------

__device__ __forceinline__ void flag_st(int* p, int v) {
    __hip_atomic_store(p, v, __ATOMIC_RELAXED, __HIP_MEMORY_SCOPE_AGENT);
}
__device__ __forceinline__ int flag_ld(const int* p) {
    return __hip_atomic_load(p, __ATOMIC_RELAXED, __HIP_MEMORY_SCOPE_AGENT);
}
__device__ __forceinline__ void ex_store(float* p, float v) {
    __hip_atomic_store(p, v, __ATOMIC_RELAXED, __HIP_MEMORY_SCOPE_AGENT);
}

// wave0: active lanes poll their flag word until >= tgt. Bounded spin ->
// a protocol failure degrades to absmax diagnostic instead of a hang.
__device__ __forceinline__ void pollwait(const int* p, int tgt, bool active) {
    if (threadIdx.x < 64) {
        int spins = 0;
        while (true) {
            int v = active ? flag_ld(p) : 0x7fffffff;
            if (__all(v >= tgt)) break;
            if (++spins > 200000) break;
            __builtin_amdgcn_s_sleep(1);
        }
    }
    __syncthreads();
}

// stage 32 rows of J floats from the exchange ring (contiguous [b][u]) into
// LDS rows of stride J+4. Loads bypass L1+L2 (sc0 sc1) -> read the LLC,
// which is exactly where the producers' agent-scope atomic stores land.
template <int J>
__device__ __forceinline__ void stageX(float* dst, const float* src) {
    constexpr int NF4 = (32 * J) / 1024;  // 8 for J=256, 4 for J=128
    constexpr int LJ = (J == 256) ? 8 : 7;
    float4 tmp[NF4];
    #pragma unroll
    for (int k = 0; k < NF4; ++k) {
        const float* p = src + (size_t)(k * 256 + threadIdx.x) * 4;
        asm volatile("global_load_dwordx4 %0, %1, off sc0 sc1"
                     : "=v"(tmp[k]) : "v"(p) : "memory");
    }
    asm volatile("s_waitcnt vmcnt(0)" ::: "memory");
    #pragma unroll
    for (int k = 0; k < NF4; ++k) {
        int i = (k * 256 + threadIdx.x) * 4;
        int b = i >> LJ;
        int j = i & (J - 1);
        *(float4*)(dst + b * (J + 4) + j) = tmp[k];
    }
}

template <int J>
__device__ __forceinline__ void zero32(float* dst) {
    for (int i = threadIdx.x; i < 32 * (J + 4); i += 256) dst[i] = 0.0f;
}

// acc{r,z,c} += w{R,Z,N} . h[row] for KB batch rows (row = b0 + k*(32/KB))
template <int KB, int J>
__device__ __forceinline__ void dot3(const float* __restrict__ w3,
                                     const float* __restrict__ hst, int b0,
                                     float* ar, float* az, float* ac) {
    const float4* wr = (const float4*)w3;
    const float4* wz = (const float4*)(w3 + J);
    const float4* wn = (const float4*)(w3 + 2 * J);
    const float* rows[KB];
    #pragma unroll
    for (int k = 0; k < KB; ++k) rows[k] = hst + (b0 + k * (32 / KB)) * (J + 4);
    #pragma unroll 4
    for (int j4 = 0; j4 < J / 4; ++j4) {
        float4 a = wr[j4];
        float4 c = wz[j4];
        float4 d = wn[j4];
        #pragma unroll
        for (int k = 0; k < KB; ++k) {
            float4 hv = *(const float4*)(rows[k] + j4 * 4);
            ar[k] = fmaf(hv.x, a.x, ar[k]); ar[k] = fmaf(hv.y, a.y, ar[k]);
            ar[k] = fmaf(hv.z, a.z, ar[k]); ar[k] = fmaf(hv.w, a.w, ar[k]);
            az[k] = fmaf(hv.x, c.x, az[k]); az[k] = fmaf(hv.y, c.y, az[k]);
            az[k] = fmaf(hv.z, c.z, az[k]); az[k] = fmaf(hv.w, c.w, az[k]);
            ac[k] = fmaf(hv.x, d.x, ac[k]); ac[k] = fmaf(hv.y, d.y, ac[k]);
            ac[k] = fmaf(hv.z, d.z, ac[k]); ac[k] = fmaf(hv.w, d.w, ac[k]);
        }
    }
}

__global__ __launch_bounds__(256) void gru_pipe_kernel(
    const float* __restrict__ x,
    const float* __restrict__ w_ih1,
    const float* __restrict__ b_ih1, const float* __restrict__ b_hh1,
    const float* __restrict__ b_ih2, const float* __restrict__ b_hh2,
    const float* __restrict__ b_ih3, const float* __restrict__ b_hh3,
    const float* __restrict__ b_ih4, const float* __restrict__ b_hh4,
    const float* __restrict__ wA_hh1,  // [256][3][256]
    const float* __restrict__ wA_ih2,  // [128][3][256]
    const float* __restrict__ wA_hh2,  // [128][3][128]
    const float* __restrict__ wA_ih3,  // [128][3][128]
    const float* __restrict__ wA_hh3,  // [128][3][128]
    const float* __restrict__ wA_ih4,  // [256][3][128]
    const float* __restrict__ wA_hh4,  // [256][3][256]
    const float* __restrict__ w_out, const float* __restrict__ b_out,
    int* __restrict__ flags,  // [8 bg][4 stages x 32 ints (128B line)]
    float* __restrict__ ex,   // [8 bg][98304] h rings
    float* __restrict__ out)  // [256][1024] pre-zeroed
{
    const int tid = threadIdx.x;
    extern __shared__ float smem[];
    __shared__ float xs[32];
    __shared__ float wsum[4][4][8];

    const int bg = blockIdx.x & 7;        // batch group (32 rows)
    const int rest = blockIdx.x >> 3;
    const int s = rest >> 3;              // stage 0..3
    const int us = rest & 7;              // unit slice 0..7

    int* fb = flags + bg * 128;           // 4 lines x 32 ints
    int* arr_own = fb + s * 32;           // this stage's 8 seq numbers

    // per-lane poll assignments (wave0 only)
    const int* pT = arr_own; int dT = -1000000000; bool aT = false;
    const int* pM = arr_own; int dM = -1000000000; bool aM = false;
    if (tid < 8) {
        if (s > 0) { pT = fb + (s - 1) * 32 + tid; dT = 1; aT = true; }
        pM = arr_own + tid; dM = 0; aM = true;
    } else if (tid < 16) {
        if (s < 3) { pT = fb + (s + 1) * 32 + (tid - 8); dT = -3; aT = true; }
    }

    float* exb = ex + (size_t)bg * 98304;
    float* h1r = exb;            // 4 slots x 32 x 256
    float* h2r = exb + 32768;    // 4 x 32 x 128
    float* h3r = exb + 49152;
    float* h4r = exb + 65536;

    if (s == 0) {
        // ---- layer 1: in=1 scalar, H=256, 32 units/slice, KB=4 ----
        float* wlds = smem;            // [32][772]
        float* hprev = smem + 24704;   // [32][260]
        {
            const float* srcw = wA_hh1 + (size_t)us * 32 * 768;
            for (int i = tid; i < 24576; i += 256) {
                int uu = i / 768, r = i - uu * 768;
                wlds[uu * 772 + r] = srcw[i];
            }
        }
        __syncthreads();
        const int ul = tid >> 3, b0 = tid & 7;
        const int u = us * 32 + ul;
        const float* wh = wlds + ul * 772;
        const float br = b_ih1[u] + b_hh1[u];
        const float bz = b_ih1[u + 256] + b_hh1[u + 256];
        const float bxn = b_ih1[u + 512];
        const float bhn = b_hh1[u + 512];
        const float wir = w_ih1[u], wiz = w_ih1[u + 256], win = w_ih1[u + 512];
        for (int t = 0; t < 1024; ++t) {
            pollwait(pT, t + dT, aT);          // downstream backpressure
            if (tid < 32) xs[tid] = x[(size_t)(bg * 32 + tid) * 1024 + t];
            pollwait(pM, t + dM, aM);          // peers done t-1
            if (t > 0) stageX<256>(hprev, h1r + (size_t)((t - 1) & 3) * 8192);
            else       zero32<256>(hprev);
            __syncthreads();
            float ar[4], az[4], axn[4], ahn[4];
            #pragma unroll
            for (int k = 0; k < 4; ++k) {
                float xv = xs[b0 + 8 * k];
                ar[k] = br + xv * wir; az[k] = bz + xv * wiz;
                axn[k] = bxn + xv * win; ahn[k] = bhn;
            }
            dot3<4, 256>(wh, hprev, b0, ar, az, ahn);
            float* hout = h1r + (size_t)(t & 3) * 8192;
            #pragma unroll
            for (int k = 0; k < 4; ++k) {
                int b = b0 + 8 * k;
                float hp = hprev[b * 260 + u];
                float r = sigmoidf_(ar[k]);
                float z = sigmoidf_(az[k]);
                float n = tanhf(axn[k] + r * ahn[k]);
                ex_store(hout + b * 256 + u, (1.f - z) * n + z * hp);
            }
            asm volatile("s_waitcnt vmcnt(0)" ::: "memory");  // h at LLC
            __syncthreads();
            if (tid == 0) flag_st(arr_own + us, t + 1);
        }
    } else if (s == 1) {
        // ---- layer 2: in=256, H=128, 16 units/slice, KB=2 ----
        float* wlds = smem;            // [16][388]
        float* hin = smem + 6208;      // [32][260]
        float* hprev = smem + 14528;   // [32][132]
        {
            const float* srcw = wA_hh2 + (size_t)us * 16 * 384;
            for (int i = tid; i < 6144; i += 256) {
                int uu = i / 384, r = i - uu * 384;
                wlds[uu * 388 + r] = srcw[i];
            }
        }
        __syncthreads();
        const int ul = tid >> 4, b0 = tid & 15;
        const int u = us * 16 + ul;
        const float* wi = wA_ih2 + (size_t)u * 768;
        const float* wh = wlds + ul * 388;
        const float br = b_ih2[u] + b_hh2[u];
        const float bz = b_ih2[u + 128] + b_hh2[u + 128];
        const float bxn = b_ih2[u + 256];
        const float bhn = b_hh2[u + 256];
        for (int t = 0; t < 1024; ++t) {
            pollwait(pT, t + dT, aT);   // upstream >= t+1, downstream >= t-3
            stageX<256>(hin, h1r + (size_t)(t & 3) * 8192);
            __syncthreads();
            float ar[2] = {br, br}, az[2] = {bz, bz};
            float axn[2] = {bxn, bxn}, ahn[2] = {bhn, bhn};
            dot3<2, 256>(wi, hin, b0, ar, az, axn);
            pollwait(pM, t + dM, aM);   // peers (hidden under ih dot)
            if (t > 0) stageX<128>(hprev, h2r + (size_t)((t - 1) & 3) * 4096);
            else       zero32<128>(hprev);
            __syncthreads();
            dot3<2, 128>(wh, hprev, b0, ar, az, ahn);
            float* hout = h2r + (size_t)(t & 3) * 4096;
            #pragma unroll
            for (int k = 0; k < 2; ++k) {
                int b = b0 + 16 * k;
                float hp = hprev[b * 132 + u];
                float r = sigmoidf_(ar[k]);
                float z = sigmoidf_(az[k]);
                float n = tanhf(axn[k] + r * ahn[k]);
                ex_store(hout + b * 128 + u, (1.f - z) * n + z * hp);
            }
            asm volatile("s_waitcnt vmcnt(0)" ::: "memory");
            __syncthreads();
            if (tid == 0) flag_st(arr_own + us, t + 1);
        }
    } else if (s == 2) {
        // ---- layer 3: in=128, H=128, 16 units/slice, KB=2 ----
        float* wlds = smem;            // [16][388]
        float* hin = smem + 6208;      // [32][132]
        float* hprev = smem + 10432;   // [32][132]
        {
            const float* srcw = wA_hh3 + (size_t)us * 16 * 384;
            for (int i = tid; i < 6144; i += 256) {
                int uu = i / 384, r = i - uu * 384;
                wlds[uu * 388 + r] = srcw[i];
            }
        }
        __syncthreads();
        const int ul = tid >> 4, b0 = tid & 15;
        const int u = us * 16 + ul;
        const float* wi = wA_ih3 + (size_t)u * 384;
        const float* wh = wlds + ul * 388;
        const float br = b_ih3[u] + b_hh3[u];
        const float bz = b_ih3[u + 128] + b_hh3[u + 128];
        const float bxn = b_ih3[u + 256];
        const float bhn = b_hh3[u + 256];
        for (int t = 0; t < 1024; ++t) {
            pollwait(pT, t + dT, aT);
            stageX<128>(hin, h2r + (size_t)(t & 3) * 4096);
            __syncthreads();
            float ar[2] = {br, br}, az[2] = {bz, bz};
            float axn[2] = {bxn, bxn}, ahn[2] = {bhn, bhn};
            dot3<2, 128>(wi, hin, b0, ar, az, axn);
            pollwait(pM, t + dM, aM);
            if (t > 0) stageX<128>(hprev, h3r + (size_t)((t - 1) & 3) * 4096);
            else       zero32<128>(hprev);
            __syncthreads();
            dot3<2, 128>(wh, hprev, b0, ar, az, ahn);
            float* hout = h3r + (size_t)(t & 3) * 4096;
            #pragma unroll
            for (int k = 0; k < 2; ++k) {
                int b = b0 + 16 * k;
                float hp = hprev[b * 132 + u];
                float r = sigmoidf_(ar[k]);
                float z = sigmoidf_(az[k]);
                float n = tanhf(axn[k] + r * ahn[k]);
                ex_store(hout + b * 128 + u, (1.f - z) * n + z * hp);
            }
            asm volatile("s_waitcnt vmcnt(0)" ::: "memory");
            __syncthreads();
            if (tid == 0) flag_st(arr_own + us, t + 1);
        }
    } else {
        // ---- layer 4: in=128, H=256, 32 units/slice, KB=4, + projection ----
        float* wlds = smem;            // [32][772]
        float* hin = smem + 24704;     // [32][132]
        float* hprev = smem + 28928;   // [32][260]
        {
            const float* srcw = wA_hh4 + (size_t)us * 32 * 768;
            for (int i = tid; i < 24576; i += 256) {
                int uu = i / 768, r = i - uu * 768;
                wlds[uu * 772 + r] = srcw[i];
            }
        }
        __syncthreads();
        const int ul = tid >> 3, b0 = tid & 7;
        const int u = us * 32 + ul;
        const float* wi = wA_ih4 + (size_t)u * 384;
        const float* wh = wlds + ul * 772;
        const float br = b_ih4[u] + b_hh4[u];
        const float bz = b_ih4[u + 256] + b_hh4[u + 256];
        const float bxn = b_ih4[u + 512];
        const float bhn = b_hh4[u + 512];
        const float wo = w_out[u];
        for (int t = 0; t < 1024; ++t) {
            pollwait(pT, t + dT, aT);   // upstream only
            stageX<128>(hin, h3r + (size_t)(t & 3) * 4096);
            __syncthreads();
            float ar[4], az[4], axn[4], ahn[4];
            #pragma unroll
            for (int k = 0; k < 4; ++k) {
                ar[k] = br; az[k] = bz; axn[k] = bxn; ahn[k] = bhn;
            }
            dot3<4, 128>(wi, hin, b0, ar, az, axn);
            pollwait(pM, t + dM, aM);
            if (t > 0) stageX<256>(hprev, h4r + (size_t)((t - 1) & 3) * 8192);
            else       zero32<256>(hprev);
            __syncthreads();
            dot3<4, 256>(wh, hprev, b0, ar, az, ahn);
            float* hout = h4r + (size_t)(t & 3) * 8192;
            float pk[4];
            #pragma unroll
            for (int k = 0; k < 4; ++k) {
                int b = b0 + 8 * k;
                float hp = hprev[b * 260 + u];
                float r = sigmoidf_(ar[k]);
                float z = sigmoidf_(az[k]);
                float n = tanhf(axn[k] + r * ahn[k]);
                float hnew = (1.f - z) * n + z * hp;
                ex_store(hout + b * 256 + u, hnew);
                pk[k] = wo * hnew;
            }
            #pragma unroll
            for (int k = 0; k < 4; ++k) {
                pk[k] += __shfl_xor(pk[k], 8, 64);
                pk[k] += __shfl_xor(pk[k], 16, 64);
                pk[k] += __shfl_xor(pk[k], 32, 64);
            }
            if ((tid & 63) < 8) {
                int w = tid >> 6;
                #pragma unroll
                for (int k = 0; k < 4; ++k) wsum[w][k][tid & 7] = pk[k];
            }
            asm volatile("s_waitcnt vmcnt(0)" ::: "memory");
            __syncthreads();
            if (tid == 0) flag_st(arr_own + us, t + 1);
            if (tid < 32) {
                int k = tid >> 3, bb = tid & 7;
                float ssum = wsum[0][k][bb] + wsum[1][k][bb] +
                             wsum[2][k][bb] + wsum[3][k][bb];
                if (us == 0) ssum += b_out[0];
                atomicAdd(out + (size_t)(bg * 32 + bb + 8 * k) * 1024 + t, ssum);
            }
        }
    }
}

extern "C" void kernel_launch(void* const* d_in, const int* in_sizes, int n_in,
                              void* d_out, int out_size, void* d_ws, size_t ws_size,
                              hipStream_t stream) {
    const float* x     = (const float*)d_in[0];
    const float* w_ih1 = (const float*)d_in[1];
    const float* w_hh1 = (const float*)d_in[2];
    const float* b_ih1 = (const float*)d_in[3];
    const float* b_hh1 = (const float*)d_in[4];
    const float* w_ih2 = (const float*)d_in[5];
    const float* w_hh2 = (const float*)d_in[6];
    const float* b_ih2 = (const float*)d_in[7];
    const float* b_hh2 = (const float*)d_in[8];
    const float* w_ih3 = (const float*)d_in[9];
    const float* w_hh3 = (const float*)d_in[10];
    const float* b_ih3 = (const float*)d_in[11];
    const float* b_hh3 = (const float*)d_in[12];
    const float* w_ih4 = (const float*)d_in[13];
    const float* w_hh4 = (const float*)d_in[14];
    const float* b_ih4 = (const float*)d_in[15];
    const float* b_hh4 = (const float*)d_in[16];
    const float* w_out = (const float*)d_in[17];
    const float* b_out = (const float*)d_in[18];

    float* ws = (float*)d_ws;
    float* wA_hh1 = ws;                  // 196608
    float* wA_ih2 = wA_hh1 + 196608;     //  98304
    float* wA_hh2 = wA_ih2 + 98304;      //  49152
    float* wA_ih3 = wA_hh2 + 49152;      //  49152
    float* wA_hh3 = wA_ih3 + 49152;      //  49152
    float* wA_ih4 = wA_hh3 + 49152;      //  98304
    float* wA_hh4 = wA_ih4 + 98304;      // 196608
    float* ex     = wA_hh4 + 196608;     // 786432 (8 bg x 98304)
    int*   flags  = (int*)(ex + 786432); // 8 x 128 ints

    hipMemsetAsync(flags, 0, 1024 * sizeof(int), stream);
    hipMemsetAsync(d_out, 0, 256 * 1024 * sizeof(float), stream);

    prep_k<<<768, 256, 0, stream>>>(w_hh1, wA_hh1, 256, 256);
    prep_k<<<384, 256, 0, stream>>>(w_ih2, wA_ih2, 128, 256);
    prep_k<<<192, 256, 0, stream>>>(w_hh2, wA_hh2, 128, 128);
    prep_k<<<192, 256, 0, stream>>>(w_ih3, wA_ih3, 128, 128);
    prep_k<<<192, 256, 0, stream>>>(w_hh3, wA_hh3, 128, 128);
    prep_k<<<384, 256, 0, stream>>>(w_ih4, wA_ih4, 256, 128);
    prep_k<<<768, 256, 0, stream>>>(w_hh4, wA_hh4, 256, 256);

    // 149KB dynamic LDS: 1 block/CU; grid=256 => all blocks co-resident.
    const int dyn_lds = 37248 * (int)sizeof(float);
    (void)hipFuncSetAttribute((const void*)gru_pipe_kernel,
                              hipFuncAttributeMaxDynamicSharedMemorySize, dyn_lds);

    gru_pipe_kernel<<<256, 256, dyn_lds, stream>>>(
        x, w_ih1, b_ih1, b_hh1, b_ih2, b_hh2, b_ih3, b_hh3, b_ih4, b_hh4,
        wA_hh1, wA_ih2, wA_hh2, wA_ih3, wA_hh3, wA_ih4, wA_hh4,
        w_out, b_out, flags, ex, (float*)d_out);
}